// Round 12
// baseline (1022.871 us; speedup 1.0000x reference)
//
#include <hip/hip_runtime.h>
#include <stdint.h>

// Problem constants
#define B_   16
#define N_   4096
#define M_   1024
#define NT   (B_*M_*32)      // 524288 samples
#define BM   (B_*M_)         // 16384 (b,m) groups

typedef unsigned short u16;
typedef unsigned long long u64;
typedef __attribute__((ext_vector_type(8))) short short8;   // 8 bf16 (4 VGPRs)
typedef __attribute__((ext_vector_type(4))) float f32x4;    // MFMA C/D

__device__ __forceinline__ float bf2f(u16 u){
    return __uint_as_float(((unsigned int)u) << 16);
}
__device__ __forceinline__ u16 f2bf(float f){
    unsigned int u = __float_as_uint(f);
    return (u16)((u + 0x7FFFu + ((u >> 16) & 1u)) >> 16);
}

// ---------------------------------------------------------------------------
// features [B][64][N] f32 -> featT [B][N][64] f32
// ---------------------------------------------------------------------------
__global__ __launch_bounds__(256) void k_feat(const float* __restrict__ feat,
                                              float* __restrict__ featT){
    __shared__ float tile[64][65];
    int b  = blockIdx.y;
    int n0 = blockIdx.x * 64;
    for (int t = threadIdx.x; t < 4096; t += 256){
        int c = t >> 6, n = t & 63;
        tile[c][n] = feat[((size_t)(b*64 + c))*N_ + n0 + n];
    }
    __syncthreads();
    for (int t = threadIdx.x; t < 4096; t += 256){
        int n = t >> 6, c = t & 63;
        featT[((size_t)(b*N_) + n0 + n)*64 + c] = tile[c][n];
    }
}

// ---------------------------------------------------------------------------
// exact KNN (32 smallest of 4096): value-domain linear bucket select.
// ---------------------------------------------------------------------------
__global__ __launch_bounds__(256) void k_knn(const float* __restrict__ locF,
                                             const float* __restrict__ nlocF,
                                             int* __restrict__ idxOut){
    const int tid  = threadIdx.x;
    const int lane = tid & 63, wv = tid >> 6;
    const int q    = blockIdx.x;
    const int b    = q >> 10, m = q & 1023;

    float qx = nlocF[(size_t)(b*M_ + m)*3 + 0];
    float qy = nlocF[(size_t)(b*M_ + m)*3 + 1];
    float qz = nlocF[(size_t)(b*M_ + m)*3 + 2];
    float y2 = __fadd_rn(__fadd_rn(__fmul_rn(qx,qx), __fmul_rn(qy,qy)), __fmul_rn(qz,qz));

    unsigned int key[16];
    const float* lb = locF + (size_t)b*N_*3;
    #pragma unroll
    for (int i = 0; i < 16; ++i){
        int n = i*256 + tid;
        float lx = lb[n*3+0], ly = lb[n*3+1], lz = lb[n*3+2];
        float x2 = __fadd_rn(__fadd_rn(__fmul_rn(lx,lx), __fmul_rn(ly,ly)), __fmul_rn(lz,lz));
        float dt = __fadd_rn(__fadd_rn(__fmul_rn(qx,lx), __fmul_rn(qy,ly)), __fmul_rn(qz,lz));
        float d2 = __fsub_rn(__fadd_rn(y2, x2), __fmul_rn(2.0f, dt));
        d2 = fmaxf(d2, 0.0f);
        key[i] = __float_as_uint(d2);
    }

    __shared__ unsigned int hist[4][256];
    __shared__ float wmm[4][2];
    __shared__ u64 cand[128];
    __shared__ int sOut[32];
    __shared__ int outCnt, candCnt;

    float lmin = 3.4e38f, lmax = 0.0f;
    #pragma unroll
    for (int i = 0; i < 16; ++i){
        float kf = __uint_as_float(key[i]);
        lmin = fminf(lmin, kf); lmax = fmaxf(lmax, kf);
    }
    #pragma unroll
    for (int st = 1; st < 64; st <<= 1){
        lmin = fminf(lmin, __shfl_xor(lmin, st, 64));
        lmax = fmaxf(lmax, __shfl_xor(lmax, st, 64));
    }
    if (tid == 0){ outCnt = 0; candCnt = 0; }
    if (lane == 0){ wmm[wv][0] = lmin; wmm[wv][1] = lmax; }
    __syncthreads();
    float lo = fminf(fminf(wmm[0][0], wmm[1][0]), fminf(wmm[2][0], wmm[3][0]));
    float hi = fmaxf(fmaxf(wmm[0][1], wmm[1][1]), fmaxf(wmm[2][1], wmm[3][1]));

    unsigned int act = 0xFFFFu;
    int bkt[16];
    int R = 32;

    for (int lvl = 0; lvl < 8; ++lvl){
        float scale = 255.0f / fmaxf(hi - lo, 1e-35f);
        ((uint4*)hist)[tid] = make_uint4(0,0,0,0);
        __syncthreads();
        #pragma unroll
        for (int i = 0; i < 16; ++i){
            if (act & (1u << i)){
                float kf = __uint_as_float(key[i]);
                int bb = (int)((kf - lo) * scale);
                bb = bb < 0 ? 0 : (bb > 255 ? 255 : bb);
                bkt[i] = bb;
                atomicAdd(&hist[wv][bb], 1u);
            }
        }
        __syncthreads();
        uint4 ha = *(const uint4*)&hist[0][lane << 2];
        uint4 hb = *(const uint4*)&hist[1][lane << 2];
        uint4 hc = *(const uint4*)&hist[2][lane << 2];
        uint4 hd = *(const uint4*)&hist[3][lane << 2];
        uint4 h = make_uint4(ha.x+hb.x+hc.x+hd.x, ha.y+hb.y+hc.y+hd.y,
                             ha.z+hb.z+hc.z+hd.z, ha.w+hb.w+hc.w+hd.w);
        int tot = (int)(h.x + h.y + h.z + h.w);
        int v = tot;
        #pragma unroll
        for (int st = 1; st < 64; st <<= 1){
            int u = __shfl_up(v, st, 64);
            if (lane >= st) v += u;
        }
        u64 bal = __ballot(v >= R);
        int Ls = __ffsll((unsigned long long)bal) - 1;
        int exclS = __shfl(v - tot, Ls, 64);
        int hx = __shfl((int)h.x, Ls, 64), hy = __shfl((int)h.y, Ls, 64);
        int hz = __shfl((int)h.z, Ls, 64), hw = __shfl((int)h.w, Ls, 64);
        int c0 = exclS + hx, c1 = c0 + hy, c2 = c1 + hz;
        int jj    = (c0 >= R) ? 0 : (c1 >= R) ? 1 : (c2 >= R) ? 2 : 3;
        int below = (jj == 0) ? exclS : (jj == 1) ? c0 : (jj == 2) ? c1 : c2;
        int cnt   = (jj == 0) ? hx : (jj == 1) ? hy : (jj == 2) ? hz : hw;
        int qb = Ls*4 + jj;
        R -= below;
        bool brk = (cnt <= 128) || (lvl == 7);

        float nlo = 3.4e38f, nhi = 0.0f;
        #pragma unroll
        for (int i = 0; i < 16; ++i){
            if (act & (1u << i)){
                int bb = bkt[i];
                if (bb < qb){
                    int pos = atomicAdd(&outCnt, 1);
                    if (pos < 32) sOut[pos] = i*256 + tid;
                    act &= ~(1u << i);
                } else if (bb > qb){
                    act &= ~(1u << i);
                } else if (!brk){
                    float kf = __uint_as_float(key[i]);
                    nlo = fminf(nlo, kf); nhi = fmaxf(nhi, kf);
                }
            }
        }
        if (brk) break;
        #pragma unroll
        for (int st = 1; st < 64; st <<= 1){
            nlo = fminf(nlo, __shfl_xor(nlo, st, 64));
            nhi = fmaxf(nhi, __shfl_xor(nhi, st, 64));
        }
        __syncthreads();
        if (lane == 0){ wmm[wv][0] = nlo; wmm[wv][1] = nhi; }
        __syncthreads();
        lo = fminf(fminf(wmm[0][0], wmm[1][0]), fminf(wmm[2][0], wmm[3][0]));
        hi = fmaxf(fmaxf(wmm[0][1], wmm[1][1]), fmaxf(wmm[2][1], wmm[3][1]));
    }

    #pragma unroll
    for (int i = 0; i < 16; ++i){
        if (act & (1u << i)){
            int pos = atomicAdd(&candCnt, 1);
            if (pos < 128) cand[pos] = (((u64)key[i]) << 32) | (unsigned int)(i*256 + tid);
        }
    }
    __syncthreads();
    int c = candCnt < 128 ? candCnt : 128;
    int base = outCnt;
    if (tid < c){
        u64 me = cand[tid];
        int rank = 0;
        for (int j = 0; j < c; ++j) rank += (cand[j] < me) ? 1 : 0;
        if (rank < R) sOut[base + rank] = (int)(me & 0xFFFFFFFFull);
    }
    __syncthreads();
    if (tid < 32) idxOut[(size_t)q*32 + tid] = sOut[tid];
}

// ---------------------------------------------------------------------------
// conv1 tiled: thread = (o-block 16, s-block 4); gather staged via LDS.
// ---------------------------------------------------------------------------
__global__ __launch_bounds__(256) void k_conv1t(const int* __restrict__ idx,
                                                const float* __restrict__ locF,
                                                const float* __restrict__ nlocF,
                                                const float* __restrict__ featT,
                                                const float* __restrict__ W1,
                                                u16* __restrict__ y1){
    __shared__ float Wl[67*64];     // [c][o]
    __shared__ float At[16*256];    // [c_local][s_local]
    const int t  = threadIdx.x;
    const int s0 = blockIdx.x * 256;
    for (int i = t; i < 67*64; i += 256){
        int c = i >> 6, o = i & 63;
        Wl[i] = W1[o*67 + c];
    }
    __syncthreads();

    const int ob = t >> 6;
    const int sb = t & 63;
    const int o0 = ob*16;
    const int b  = s0 >> 15;
    float acc[16][4];

    {
        int4 nn = *(const int4*)&idx[s0 + sb*4];
        int ns[4] = {nn.x, nn.y, nn.z, nn.w};
        int m = ((s0 + sb*4) >> 5) & 1023;
        float qx = nlocF[(size_t)(b*M_ + m)*3 + 0];
        float qy = nlocF[(size_t)(b*M_ + m)*3 + 1];
        float qz = nlocF[(size_t)(b*M_ + m)*3 + 2];
        float r0[4], r1[4], r2[4];
        #pragma unroll
        for (int j = 0; j < 4; ++j){
            int n = ns[j]; if ((unsigned)n >= N_) n = 0;
            const float* lp = &locF[(size_t)(b*N_ + n)*3];
            r0[j] = lp[0] - qx; r1[j] = lp[1] - qy; r2[j] = lp[2] - qz;
        }
        #pragma unroll
        for (int i = 0; i < 16; ++i){
            float w0 = Wl[o0 + i], w1 = Wl[64 + o0 + i], w2 = Wl[128 + o0 + i];
            #pragma unroll
            for (int j = 0; j < 4; ++j)
                acc[i][j] = fmaf(w2, r2[j], fmaf(w1, r1[j], w0*r0[j]));
        }
    }

    for (int pass = 0; pass < 4; ++pass){
        __syncthreads();
        {
            int n = idx[s0 + t]; if ((unsigned)n >= N_) n = 0;
            const float4* fr = (const float4*)&featT[((size_t)(b*N_) + n)*64 + pass*16];
            #pragma unroll
            for (int q = 0; q < 4; ++q){
                float4 f = fr[q];
                At[(q*4+0)*256 + t] = f.x;
                At[(q*4+1)*256 + t] = f.y;
                At[(q*4+2)*256 + t] = f.z;
                At[(q*4+3)*256 + t] = f.w;
            }
        }
        __syncthreads();
        const float4* Wrow = (const float4*)&Wl[(3 + pass*16)*64];
        #pragma unroll
        for (int c = 0; c < 16; ++c){
            float4 a = *(const float4*)&At[c*256 + sb*4];
            float av[4] = {a.x, a.y, a.z, a.w};
            #pragma unroll
            for (int q = 0; q < 4; ++q){
                float4 w = Wrow[c*16 + ob*4 + q];
                float wv[4] = {w.x, w.y, w.z, w.w};
                #pragma unroll
                for (int r = 0; r < 4; ++r)
                    #pragma unroll
                    for (int j = 0; j < 4; ++j)
                        acc[q*4+r][j] = fmaf(wv[r], av[j], acc[q*4+r][j]);
            }
        }
    }
    #pragma unroll
    for (int i = 0; i < 16; ++i){
        ushort4 pk;
        pk.x = f2bf(acc[i][0]); pk.y = f2bf(acc[i][1]);
        pk.z = f2bf(acc[i][2]); pk.w = f2bf(acc[i][3]);
        *(ushort4*)&y1[(size_t)(o0+i)*NT + s0 + sb*4] = pk;
    }
}

// ---------------------------------------------------------------------------
// conv2 tiled
// ---------------------------------------------------------------------------
__global__ __launch_bounds__(256) void k_conv2t(const u16* __restrict__ yin,
                                                const float* __restrict__ W2,
                                                const float* __restrict__ prm,
                                                u16* __restrict__ yout){
    __shared__ float Wl[64*64];     // [c][o]
    __shared__ float At[16*256];
    __shared__ float sS[64], sT[64];
    const int t  = threadIdx.x;
    const int s0 = blockIdx.x * 256;
    for (int i = t; i < 64*64; i += 256){
        int c = i >> 6, o = i & 63;
        Wl[i] = W2[o*64 + c];
    }
    if (t < 64){ sS[t] = prm[t]; sT[t] = prm[64 + t]; }

    const int ob = t >> 6, sb = t & 63, o0 = ob*16;
    float acc[16][4];
    #pragma unroll
    for (int i = 0; i < 16; ++i)
        #pragma unroll
        for (int j = 0; j < 4; ++j) acc[i][j] = 0.0f;

    for (int pass = 0; pass < 4; ++pass){
        __syncthreads();
        #pragma unroll
        for (int rep = 0; rep < 2; ++rep){
            int v = rep*256 + t;
            int row = v >> 5, ch = v & 31;
            int c = pass*16 + row;
            uint4 pk = *(const uint4*)&yin[(size_t)c*NT + s0 + ch*8];
            float sc = sS[c], tt = sT[c];
            unsigned int w4[4] = {pk.x, pk.y, pk.z, pk.w};
            float f[8];
            #pragma unroll
            for (int q = 0; q < 4; ++q){
                f[2*q]   = fmaxf(fmaf(bf2f((u16)(w4[q] & 0xFFFF)), sc, tt), 0.0f);
                f[2*q+1] = fmaxf(fmaf(bf2f((u16)(w4[q] >> 16)),   sc, tt), 0.0f);
            }
            float4 f1 = {f[0], f[1], f[2], f[3]};
            float4 f2 = {f[4], f[5], f[6], f[7]};
            *(float4*)&At[row*256 + ch*8]     = f1;
            *(float4*)&At[row*256 + ch*8 + 4] = f2;
        }
        __syncthreads();
        const float4* Wrow = (const float4*)&Wl[(pass*16)*64];
        #pragma unroll
        for (int c = 0; c < 16; ++c){
            float4 a = *(const float4*)&At[c*256 + sb*4];
            float av[4] = {a.x, a.y, a.z, a.w};
            #pragma unroll
            for (int q = 0; q < 4; ++q){
                float4 w = Wrow[c*16 + ob*4 + q];
                float wv[4] = {w.x, w.y, w.z, w.w};
                #pragma unroll
                for (int r = 0; r < 4; ++r)
                    #pragma unroll
                    for (int j = 0; j < 4; ++j)
                        acc[q*4+r][j] = fmaf(wv[r], av[j], acc[q*4+r][j]);
            }
        }
    }
    #pragma unroll
    for (int i = 0; i < 16; ++i){
        ushort4 pk;
        pk.x = f2bf(acc[i][0]); pk.y = f2bf(acc[i][1]);
        pk.z = f2bf(acc[i][2]); pk.w = f2bf(acc[i][3]);
        *(ushort4*)&yout[(size_t)(o0+i)*NT + s0 + sb*4] = pk;
    }
}

// ---------------------------------------------------------------------------
// conv3 via MFMA, operands swapped: A = activations (m=sample), B = W3
// (n=channel) -> D row = sample, col = channel. k-group (32 samples) = two
// m-tiles -> epilogue is 8-value in-reg reduce + 2-stage cross-quad butterfly
// (128 shuffles/thread vs 1024 in the old layout). gmax/gmin now [group][o]
// (coalesced 64B writes). Stage-A writes bank-staggered via (i+sg)&7.
// ---------------------------------------------------------------------------
__global__ __launch_bounds__(256) void k_conv3m(const u16* __restrict__ yin,
                                                const float* __restrict__ W3,
                                                const float* __restrict__ prm,
                                                float* __restrict__ gsum, float* __restrict__ gsq,
                                                float* __restrict__ gmax, float* __restrict__ gmin){
    __shared__ uint4 bfA[2048];     // act frags: (mtg*2+kk)*64 + quad*16 + m15  (32 KB)
    __shared__ uint4 bfB[1024];     // W3 frags:  (nt*2+kk)*64 + lane            (16 KB)
    __shared__ float sS[64], sT[64];
    __shared__ float sSum[128], sSq[128];
    const int t  = threadIdx.x;
    const int s0 = blockIdx.x * 256;

    if (t < 64){ sS[t] = prm[t]; sT[t] = prm[64 + t]; }
    if (t < 128){ sSum[t] = 0.0f; sSq[t] = 0.0f; }
    __syncthreads();

    // stage B: W3 [128][64] f32 -> bf16 frags (n=channel within tile)
    #pragma unroll
    for (int rep = 0; rep < 4; ++rep){
        int cid = rep*256 + t;
        int ln  = cid & 63;
        int kk  = (cid >> 6) & 1;
        int nt  = cid >> 7;
        int o   = nt*16 + (ln & 15);
        int k0  = kk*32 + (ln >> 4)*8;
        const float* wp = &W3[o*64 + k0];
        unsigned int d[4];
        #pragma unroll
        for (int h = 0; h < 4; ++h)
            d[h] = (unsigned int)f2bf(wp[2*h]) | (((unsigned int)f2bf(wp[2*h+1])) << 16);
        bfB[cid] = make_uint4(d[0], d[1], d[2], d[3]);
    }

    // stage A: y2 channel-major; affine+relu; m=sample frags
    {
        int oct = t >> 5;            // channels oct*8..+7: kk=oct>>2, qd=oct&3
        int sg  = t & 31;            // samples sg*8..+7 (local)
        int c0  = oct*8;
        int kk  = oct >> 2;
        int qd  = oct & 3;
        u16 rb[8][8];                // [j (=c-c0)][i (=sample)]
        #pragma unroll
        for (int j = 0; j < 8; ++j){
            int c = c0 + j;
            uint4 pk = *(const uint4*)&yin[(size_t)c*NT + s0 + sg*8];
            float sc = sS[c], tb = sT[c];
            unsigned int w4[4] = {pk.x, pk.y, pk.z, pk.w};
            #pragma unroll
            for (int h = 0; h < 4; ++h){
                rb[j][2*h]   = f2bf(fmaxf(fmaf(bf2f((u16)(w4[h] & 0xFFFF)), sc, tb), 0.0f));
                rb[j][2*h+1] = f2bf(fmaxf(fmaf(bf2f((u16)(w4[h] >> 16)),   sc, tb), 0.0f));
            }
        }
        #pragma unroll
        for (int ii = 0; ii < 8; ++ii){
            int i   = (ii + sg) & 7;        // bank stagger across sg
            int s   = sg*8 + i;
            int mtg = s >> 4, m15 = s & 15;
            int cb  = (mtg*2 + kk)*64 + qd*16 + m15;
            unsigned int d[4];
            #pragma unroll
            for (int h = 0; h < 4; ++h)
                d[h] = (unsigned int)rb[2*h][i] | (((unsigned int)rb[2*h+1][i]) << 16);
            bfA[cb] = make_uint4(d[0], d[1], d[2], d[3]);
        }
    }
    __syncthreads();

    // MFMA: wave w -> m-tiles 4w..4w+3 (samples w*64..+63), all 8 n-tiles
    const int w = t >> 6, lane = t & 63;
    f32x4 acc[4][8];
    #pragma unroll
    for (int mt = 0; mt < 4; ++mt)
        #pragma unroll
        for (int nt = 0; nt < 8; ++nt)
            acc[mt][nt] = (f32x4){0.0f, 0.0f, 0.0f, 0.0f};

    #pragma unroll
    for (int kk = 0; kk < 2; ++kk){
        short8 af[4];
        #pragma unroll
        for (int mt = 0; mt < 4; ++mt)
            af[mt] = *((const short8*)&bfA[((4*w + mt)*2 + kk)*64 + lane]);
        #pragma unroll
        for (int nt = 0; nt < 8; ++nt){
            short8 bfr = *((const short8*)&bfB[(nt*2 + kk)*64 + lane]);
            #pragma unroll
            for (int mt = 0; mt < 4; ++mt)
                acc[mt][nt] = __builtin_amdgcn_mfma_f32_16x16x32_bf16(af[mt], bfr, acc[mt][nt], 0, 0, 0);
        }
    }

    // epilogue: group g (32 samples) = m-tiles (2g,2g+1). In-reg 8-value
    // reduce, then 2-stage cross-quad butterfly; quad0 writes coalesced rows.
    float stS[8], stQ[8];
    #pragma unroll
    for (int nt = 0; nt < 8; ++nt){ stS[nt] = 0.0f; stQ[nt] = 0.0f; }

    #pragma unroll
    for (int g = 0; g < 2; ++g){
        const size_t gg = (size_t)(blockIdx.x*8 + w*2 + g);
        #pragma unroll
        for (int nt = 0; nt < 8; ++nt){
            f32x4 a0 = acc[2*g][nt], a1 = acc[2*g+1][nt];
            float mx = fmaxf(fmaxf(fmaxf(a0[0], a0[1]), fmaxf(a0[2], a0[3])),
                             fmaxf(fmaxf(a1[0], a1[1]), fmaxf(a1[2], a1[3])));
            float mn = fminf(fminf(fminf(a0[0], a0[1]), fminf(a0[2], a0[3])),
                             fminf(fminf(a1[0], a1[1]), fminf(a1[2], a1[3])));
            float sm = (a0[0]+a0[1]) + (a0[2]+a0[3]) + (a1[0]+a1[1]) + (a1[2]+a1[3]);
            float sq = a0[0]*a0[0];
            sq = fmaf(a0[1], a0[1], sq); sq = fmaf(a0[2], a0[2], sq); sq = fmaf(a0[3], a0[3], sq);
            sq = fmaf(a1[0], a1[0], sq); sq = fmaf(a1[1], a1[1], sq); sq = fmaf(a1[2], a1[2], sq);
            sq = fmaf(a1[3], a1[3], sq);
            #pragma unroll
            for (int st = 16; st < 64; st <<= 1){
                mx = fmaxf(mx, __shfl_xor(mx, st, 64));
                mn = fminf(mn, __shfl_xor(mn, st, 64));
                sm += __shfl_xor(sm, st, 64);
                sq += __shfl_xor(sq, st, 64);
            }
            if (lane < 16){
                gmax[gg*128 + nt*16 + lane] = mx;
                gmin[gg*128 + nt*16 + lane] = mn;
            }
            stS[nt] += sm; stQ[nt] += sq;
        }
    }
    if (lane < 16){
        #pragma unroll
        for (int nt = 0; nt < 8; ++nt){
            atomicAdd(&sSum[nt*16 + lane], stS[nt]);
            atomicAdd(&sSq[nt*16 + lane],  stQ[nt]);
        }
    }
    __syncthreads();
    if (t < 128){
        atomicAdd(&gsum[t], sSum[t]);
        atomicAdd(&gsq[t],  sSq[t]);
    }
}

// ---------------------------------------------------------------------------
// per-channel sum/sumsq over stored y (bf16 channel-major), vectorized
// ---------------------------------------------------------------------------
__global__ __launch_bounds__(256) void k_stats(const u16* __restrict__ y,
                                               float* __restrict__ sum,
                                               float* __restrict__ sumsq){
    int c = blockIdx.x, chunk = blockIdx.y;
    size_t base = (size_t)c*NT + (size_t)chunk*16384;
    const uint2* p = (const uint2*)(y + base);
    float s = 0.0f, qq = 0.0f;
    for (int i = threadIdx.x; i < 4096; i += 256){
        uint2 v = p[i];
        float v0 = bf2f((u16)(v.x & 0xFFFF)), v1 = bf2f((u16)(v.x >> 16));
        float v2 = bf2f((u16)(v.y & 0xFFFF)), v3 = bf2f((u16)(v.y >> 16));
        s += v0 + v1 + v2 + v3;
        qq = fmaf(v0, v0, qq); qq = fmaf(v1, v1, qq);
        qq = fmaf(v2, v2, qq); qq = fmaf(v3, v3, qq);
    }
    #pragma unroll
    for (int off = 32; off > 0; off >>= 1){
        s  += __shfl_down(s,  off, 64);
        qq += __shfl_down(qq, off, 64);
    }
    __shared__ float aS[4], aQ[4];
    int wave = threadIdx.x >> 6, lane = threadIdx.x & 63;
    if (lane == 0){ aS[wave] = s; aQ[wave] = qq; }
    __syncthreads();
    if (threadIdx.x == 0){
        atomicAdd(&sum[c],   aS[0] + aS[1] + aS[2] + aS[3]);
        atomicAdd(&sumsq[c], aQ[0] + aQ[1] + aQ[2] + aQ[3]);
    }
}

// fold BN into affine: s = g*rsqrt(var+eps), t = b - mu*s
__global__ void k_fold(const float* __restrict__ sum, const float* __restrict__ sumsq,
                       const float* __restrict__ gW, const float* __restrict__ bW,
                       float* __restrict__ prm, int C){
    int c = threadIdx.x;
    if (c < C){
        const float inv = 1.0f / (float)NT;
        float mu  = sum[c] * inv;
        float var = sumsq[c] * inv - mu*mu;
        float sc  = gW[c] / sqrtf(var + 1e-5f);
        prm[c]     = sc;
        prm[C + c] = bW[c] - mu*sc;
    }
}

// out[b][o][m] = ReLU(s * (s>=0 ? gmax : gmin) + t); gmax/gmin layout [group][o]
__global__ __launch_bounds__(256) void k_final(const float* __restrict__ gmax,
                                               const float* __restrict__ gmin,
                                               const float* __restrict__ prm,
                                               float* __restrict__ out){
    int bo = blockIdx.y;
    int b = bo >> 7, o = bo & 127;
    int m = blockIdx.x*256 + threadIdx.x;
    float sc = prm[o], tt = prm[128 + o];
    size_t i = (size_t)(b*M_ + m)*128 + o;
    float v = (sc >= 0.0f) ? gmax[i] : gmin[i];
    out[((size_t)(b*128 + o))*M_ + m] = fmaxf(fmaf(v, sc, tt), 0.0f);
}

// ---------------------------------------------------------------------------
extern "C" void kernel_launch(void* const* d_in, const int* in_sizes, int n_in,
                              void* d_out, int out_size, void* d_ws, size_t ws_size,
                              hipStream_t stream){
    const float* loc  = (const float*)d_in[0];
    const float* nloc = (const float*)d_in[1];
    const float* feat = (const float*)d_in[2];
    const float* W1   = (const float*)d_in[3];
    const float* g1   = (const float*)d_in[4];
    const float* b1   = (const float*)d_in[5];
    const float* W2   = (const float*)d_in[6];
    const float* g2   = (const float*)d_in[7];
    const float* b2   = (const float*)d_in[8];
    const float* W3   = (const float*)d_in[9];
    const float* g3   = (const float*)d_in[10];
    const float* b3   = (const float*)d_in[11];
    float* out = (float*)d_out;

    char* ws = (char*)d_ws;
    float* stats = (float*)ws;                       // 512 f @ 0
    float* prm1  = (float*)(ws + 2048);              // 128 f
    float* prm2  = (float*)(ws + 2048 + 512);        // 128 f
    float* prm3  = (float*)(ws + 2048 + 1024);       // 256 f -> ends 4096
    int*   idx   = (int*)(ws + 4096);                // 2 MB
    float* gmax  = (float*)(ws + 2101248);           // 8 MB [BM][128]
    float* gmin  = (float*)(ws + 10489856);          // 8 MB
    float* featT = (float*)(ws + 18878464);          // 16 MB [B][N][64]
    u16*   y1    = (u16*)(ws + 35655680);            // 64 MB [64][NT]
    u16*   y2    = (u16*)(ws + 102764544);           // 64 MB  (ws >= 170 MB proven)

    hipMemsetAsync(stats, 0, 2048, stream);

    k_feat<<<dim3(N_/64, B_), 256, 0, stream>>>(feat, featT);
    k_knn<<<B_*M_, 256, 0, stream>>>(loc, nloc, idx);

    k_conv1t<<<NT/256, 256, 0, stream>>>(idx, loc, nloc, featT, W1, y1);
    k_stats<<<dim3(64, 32), 256, 0, stream>>>(y1, stats + 0, stats + 64);
    k_fold<<<1, 128, 0, stream>>>(stats + 0, stats + 64, g1, b1, prm1, 64);

    k_conv2t<<<NT/256, 256, 0, stream>>>(y1, W2, prm1, y2);
    k_stats<<<dim3(64, 32), 256, 0, stream>>>(y2, stats + 128, stats + 192);
    k_fold<<<1, 128, 0, stream>>>(stats + 128, stats + 192, g2, b2, prm2, 64);

    k_conv3m<<<NT/256, 256, 0, stream>>>(y2, W3, prm2, stats + 256, stats + 384, gmax, gmin);
    k_fold<<<1, 128, 0, stream>>>(stats + 256, stats + 384, g3, b3, prm3, 128);

    k_final<<<dim3(M_/256, B_*128), 256, 0, stream>>>(gmax, gmin, prm3, out);
}

// Round 13
// 444.151 us; speedup vs baseline: 2.3030x; 2.3030x over previous
//
#include <hip/hip_runtime.h>
#include <stdint.h>

// Problem constants
#define B_   16
#define N_   4096
#define M_   1024
#define NT   (B_*M_*32)      // 524288 samples
#define BM   (B_*M_)         // 16384 (b,m) groups

typedef unsigned short u16;
typedef unsigned long long u64;
typedef __attribute__((ext_vector_type(8))) short short8;   // 8 bf16 (4 VGPRs)
typedef __attribute__((ext_vector_type(4))) float f32x4;    // MFMA C/D

__device__ __forceinline__ float bf2f(u16 u){
    return __uint_as_float(((unsigned int)u) << 16);
}
__device__ __forceinline__ u16 f2bf(float f){
    unsigned int u = __float_as_uint(f);
    return (u16)((u + 0x7FFFu + ((u >> 16) & 1u)) >> 16);
}

// ---------------------------------------------------------------------------
// features [B][64][N] f32 -> featT [B][N][64] f32
// ---------------------------------------------------------------------------
__global__ __launch_bounds__(256) void k_feat(const float* __restrict__ feat,
                                              float* __restrict__ featT){
    __shared__ float tile[64][65];
    int b  = blockIdx.y;
    int n0 = blockIdx.x * 64;
    for (int t = threadIdx.x; t < 4096; t += 256){
        int c = t >> 6, n = t & 63;
        tile[c][n] = feat[((size_t)(b*64 + c))*N_ + n0 + n];
    }
    __syncthreads();
    for (int t = threadIdx.x; t < 4096; t += 256){
        int n = t >> 6, c = t & 63;
        featT[((size_t)(b*N_) + n0 + n)*64 + c] = tile[c][n];
    }
}

// ---------------------------------------------------------------------------
// exact KNN (32 smallest of 4096): value-domain linear bucket select.
// ---------------------------------------------------------------------------
__global__ __launch_bounds__(256) void k_knn(const float* __restrict__ locF,
                                             const float* __restrict__ nlocF,
                                             int* __restrict__ idxOut){
    const int tid  = threadIdx.x;
    const int lane = tid & 63, wv = tid >> 6;
    const int q    = blockIdx.x;
    const int b    = q >> 10, m = q & 1023;

    float qx = nlocF[(size_t)(b*M_ + m)*3 + 0];
    float qy = nlocF[(size_t)(b*M_ + m)*3 + 1];
    float qz = nlocF[(size_t)(b*M_ + m)*3 + 2];
    float y2 = __fadd_rn(__fadd_rn(__fmul_rn(qx,qx), __fmul_rn(qy,qy)), __fmul_rn(qz,qz));

    unsigned int key[16];
    const float* lb = locF + (size_t)b*N_*3;
    #pragma unroll
    for (int i = 0; i < 16; ++i){
        int n = i*256 + tid;
        float lx = lb[n*3+0], ly = lb[n*3+1], lz = lb[n*3+2];
        float x2 = __fadd_rn(__fadd_rn(__fmul_rn(lx,lx), __fmul_rn(ly,ly)), __fmul_rn(lz,lz));
        float dt = __fadd_rn(__fadd_rn(__fmul_rn(qx,lx), __fmul_rn(qy,ly)), __fmul_rn(qz,lz));
        float d2 = __fsub_rn(__fadd_rn(y2, x2), __fmul_rn(2.0f, dt));
        d2 = fmaxf(d2, 0.0f);
        key[i] = __float_as_uint(d2);
    }

    __shared__ unsigned int hist[4][256];
    __shared__ float wmm[4][2];
    __shared__ u64 cand[128];
    __shared__ int sOut[32];
    __shared__ int outCnt, candCnt;

    float lmin = 3.4e38f, lmax = 0.0f;
    #pragma unroll
    for (int i = 0; i < 16; ++i){
        float kf = __uint_as_float(key[i]);
        lmin = fminf(lmin, kf); lmax = fmaxf(lmax, kf);
    }
    #pragma unroll
    for (int st = 1; st < 64; st <<= 1){
        lmin = fminf(lmin, __shfl_xor(lmin, st, 64));
        lmax = fmaxf(lmax, __shfl_xor(lmax, st, 64));
    }
    if (tid == 0){ outCnt = 0; candCnt = 0; }
    if (lane == 0){ wmm[wv][0] = lmin; wmm[wv][1] = lmax; }
    __syncthreads();
    float lo = fminf(fminf(wmm[0][0], wmm[1][0]), fminf(wmm[2][0], wmm[3][0]));
    float hi = fmaxf(fmaxf(wmm[0][1], wmm[1][1]), fmaxf(wmm[2][1], wmm[3][1]));

    unsigned int act = 0xFFFFu;
    int bkt[16];
    int R = 32;

    for (int lvl = 0; lvl < 8; ++lvl){
        float scale = 255.0f / fmaxf(hi - lo, 1e-35f);
        ((uint4*)hist)[tid] = make_uint4(0,0,0,0);
        __syncthreads();
        #pragma unroll
        for (int i = 0; i < 16; ++i){
            if (act & (1u << i)){
                float kf = __uint_as_float(key[i]);
                int bb = (int)((kf - lo) * scale);
                bb = bb < 0 ? 0 : (bb > 255 ? 255 : bb);
                bkt[i] = bb;
                atomicAdd(&hist[wv][bb], 1u);
            }
        }
        __syncthreads();
        uint4 ha = *(const uint4*)&hist[0][lane << 2];
        uint4 hb = *(const uint4*)&hist[1][lane << 2];
        uint4 hc = *(const uint4*)&hist[2][lane << 2];
        uint4 hd = *(const uint4*)&hist[3][lane << 2];
        uint4 h = make_uint4(ha.x+hb.x+hc.x+hd.x, ha.y+hb.y+hc.y+hd.y,
                             ha.z+hb.z+hc.z+hd.z, ha.w+hb.w+hc.w+hd.w);
        int tot = (int)(h.x + h.y + h.z + h.w);
        int v = tot;
        #pragma unroll
        for (int st = 1; st < 64; st <<= 1){
            int u = __shfl_up(v, st, 64);
            if (lane >= st) v += u;
        }
        u64 bal = __ballot(v >= R);
        int Ls = __ffsll((unsigned long long)bal) - 1;
        int exclS = __shfl(v - tot, Ls, 64);
        int hx = __shfl((int)h.x, Ls, 64), hy = __shfl((int)h.y, Ls, 64);
        int hz = __shfl((int)h.z, Ls, 64), hw = __shfl((int)h.w, Ls, 64);
        int c0 = exclS + hx, c1 = c0 + hy, c2 = c1 + hz;
        int jj    = (c0 >= R) ? 0 : (c1 >= R) ? 1 : (c2 >= R) ? 2 : 3;
        int below = (jj == 0) ? exclS : (jj == 1) ? c0 : (jj == 2) ? c1 : c2;
        int cnt   = (jj == 0) ? hx : (jj == 1) ? hy : (jj == 2) ? hz : hw;
        int qb = Ls*4 + jj;
        R -= below;
        bool brk = (cnt <= 128) || (lvl == 7);

        float nlo = 3.4e38f, nhi = 0.0f;
        #pragma unroll
        for (int i = 0; i < 16; ++i){
            if (act & (1u << i)){
                int bb = bkt[i];
                if (bb < qb){
                    int pos = atomicAdd(&outCnt, 1);
                    if (pos < 32) sOut[pos] = i*256 + tid;
                    act &= ~(1u << i);
                } else if (bb > qb){
                    act &= ~(1u << i);
                } else if (!brk){
                    float kf = __uint_as_float(key[i]);
                    nlo = fminf(nlo, kf); nhi = fmaxf(nhi, kf);
                }
            }
        }
        if (brk) break;
        #pragma unroll
        for (int st = 1; st < 64; st <<= 1){
            nlo = fminf(nlo, __shfl_xor(nlo, st, 64));
            nhi = fmaxf(nhi, __shfl_xor(nhi, st, 64));
        }
        __syncthreads();
        if (lane == 0){ wmm[wv][0] = nlo; wmm[wv][1] = nhi; }
        __syncthreads();
        lo = fminf(fminf(wmm[0][0], wmm[1][0]), fminf(wmm[2][0], wmm[3][0]));
        hi = fmaxf(fmaxf(wmm[0][1], wmm[1][1]), fmaxf(wmm[2][1], wmm[3][1]));
    }

    #pragma unroll
    for (int i = 0; i < 16; ++i){
        if (act & (1u << i)){
            int pos = atomicAdd(&candCnt, 1);
            if (pos < 128) cand[pos] = (((u64)key[i]) << 32) | (unsigned int)(i*256 + tid);
        }
    }
    __syncthreads();
    int c = candCnt < 128 ? candCnt : 128;
    int base = outCnt;
    if (tid < c){
        u64 me = cand[tid];
        int rank = 0;
        for (int j = 0; j < c; ++j) rank += (cand[j] < me) ? 1 : 0;
        if (rank < R) sOut[base + rank] = (int)(me & 0xFFFFFFFFull);
    }
    __syncthreads();
    if (tid < 32) idxOut[(size_t)q*32 + tid] = sOut[tid];
}

// ---------------------------------------------------------------------------
// conv1 tiled: thread = (o-block 16, s-block 4); gather staged via LDS.
// ---------------------------------------------------------------------------
__global__ __launch_bounds__(256) void k_conv1t(const int* __restrict__ idx,
                                                const float* __restrict__ locF,
                                                const float* __restrict__ nlocF,
                                                const float* __restrict__ featT,
                                                const float* __restrict__ W1,
                                                u16* __restrict__ y1){
    __shared__ float Wl[67*64];     // [c][o]
    __shared__ float At[16*256];    // [c_local][s_local]
    const int t  = threadIdx.x;
    const int s0 = blockIdx.x * 256;
    for (int i = t; i < 67*64; i += 256){
        int c = i >> 6, o = i & 63;
        Wl[i] = W1[o*67 + c];
    }
    __syncthreads();

    const int ob = t >> 6;
    const int sb = t & 63;
    const int o0 = ob*16;
    const int b  = s0 >> 15;
    float acc[16][4];

    {
        int4 nn = *(const int4*)&idx[s0 + sb*4];
        int ns[4] = {nn.x, nn.y, nn.z, nn.w};
        int m = ((s0 + sb*4) >> 5) & 1023;
        float qx = nlocF[(size_t)(b*M_ + m)*3 + 0];
        float qy = nlocF[(size_t)(b*M_ + m)*3 + 1];
        float qz = nlocF[(size_t)(b*M_ + m)*3 + 2];
        float r0[4], r1[4], r2[4];
        #pragma unroll
        for (int j = 0; j < 4; ++j){
            int n = ns[j]; if ((unsigned)n >= N_) n = 0;
            const float* lp = &locF[(size_t)(b*N_ + n)*3];
            r0[j] = lp[0] - qx; r1[j] = lp[1] - qy; r2[j] = lp[2] - qz;
        }
        #pragma unroll
        for (int i = 0; i < 16; ++i){
            float w0 = Wl[o0 + i], w1 = Wl[64 + o0 + i], w2 = Wl[128 + o0 + i];
            #pragma unroll
            for (int j = 0; j < 4; ++j)
                acc[i][j] = fmaf(w2, r2[j], fmaf(w1, r1[j], w0*r0[j]));
        }
    }

    for (int pass = 0; pass < 4; ++pass){
        __syncthreads();
        {
            int n = idx[s0 + t]; if ((unsigned)n >= N_) n = 0;
            const float4* fr = (const float4*)&featT[((size_t)(b*N_) + n)*64 + pass*16];
            #pragma unroll
            for (int q = 0; q < 4; ++q){
                float4 f = fr[q];
                At[(q*4+0)*256 + t] = f.x;
                At[(q*4+1)*256 + t] = f.y;
                At[(q*4+2)*256 + t] = f.z;
                At[(q*4+3)*256 + t] = f.w;
            }
        }
        __syncthreads();
        const float4* Wrow = (const float4*)&Wl[(3 + pass*16)*64];
        #pragma unroll
        for (int c = 0; c < 16; ++c){
            float4 a = *(const float4*)&At[c*256 + sb*4];
            float av[4] = {a.x, a.y, a.z, a.w};
            #pragma unroll
            for (int q = 0; q < 4; ++q){
                float4 w = Wrow[c*16 + ob*4 + q];
                float wv[4] = {w.x, w.y, w.z, w.w};
                #pragma unroll
                for (int r = 0; r < 4; ++r)
                    #pragma unroll
                    for (int j = 0; j < 4; ++j)
                        acc[q*4+r][j] = fmaf(wv[r], av[j], acc[q*4+r][j]);
            }
        }
    }
    #pragma unroll
    for (int i = 0; i < 16; ++i){
        ushort4 pk;
        pk.x = f2bf(acc[i][0]); pk.y = f2bf(acc[i][1]);
        pk.z = f2bf(acc[i][2]); pk.w = f2bf(acc[i][3]);
        *(ushort4*)&y1[(size_t)(o0+i)*NT + s0 + sb*4] = pk;
    }
}

// ---------------------------------------------------------------------------
// conv2 tiled
// ---------------------------------------------------------------------------
__global__ __launch_bounds__(256) void k_conv2t(const u16* __restrict__ yin,
                                                const float* __restrict__ W2,
                                                const float* __restrict__ prm,
                                                u16* __restrict__ yout){
    __shared__ float Wl[64*64];     // [c][o]
    __shared__ float At[16*256];
    __shared__ float sS[64], sT[64];
    const int t  = threadIdx.x;
    const int s0 = blockIdx.x * 256;
    for (int i = t; i < 64*64; i += 256){
        int c = i >> 6, o = i & 63;
        Wl[i] = W2[o*64 + c];
    }
    if (t < 64){ sS[t] = prm[t]; sT[t] = prm[64 + t]; }

    const int ob = t >> 6, sb = t & 63, o0 = ob*16;
    float acc[16][4];
    #pragma unroll
    for (int i = 0; i < 16; ++i)
        #pragma unroll
        for (int j = 0; j < 4; ++j) acc[i][j] = 0.0f;

    for (int pass = 0; pass < 4; ++pass){
        __syncthreads();
        #pragma unroll
        for (int rep = 0; rep < 2; ++rep){
            int v = rep*256 + t;
            int row = v >> 5, ch = v & 31;
            int c = pass*16 + row;
            uint4 pk = *(const uint4*)&yin[(size_t)c*NT + s0 + ch*8];
            float sc = sS[c], tt = sT[c];
            unsigned int w4[4] = {pk.x, pk.y, pk.z, pk.w};
            float f[8];
            #pragma unroll
            for (int q = 0; q < 4; ++q){
                f[2*q]   = fmaxf(fmaf(bf2f((u16)(w4[q] & 0xFFFF)), sc, tt), 0.0f);
                f[2*q+1] = fmaxf(fmaf(bf2f((u16)(w4[q] >> 16)),   sc, tt), 0.0f);
            }
            float4 f1 = {f[0], f[1], f[2], f[3]};
            float4 f2 = {f[4], f[5], f[6], f[7]};
            *(float4*)&At[row*256 + ch*8]     = f1;
            *(float4*)&At[row*256 + ch*8 + 4] = f2;
        }
        __syncthreads();
        const float4* Wrow = (const float4*)&Wl[(pass*16)*64];
        #pragma unroll
        for (int c = 0; c < 16; ++c){
            float4 a = *(const float4*)&At[c*256 + sb*4];
            float av[4] = {a.x, a.y, a.z, a.w};
            #pragma unroll
            for (int q = 0; q < 4; ++q){
                float4 w = Wrow[c*16 + ob*4 + q];
                float wv[4] = {w.x, w.y, w.z, w.w};
                #pragma unroll
                for (int r = 0; r < 4; ++r)
                    #pragma unroll
                    for (int j = 0; j < 4; ++j)
                        acc[q*4+r][j] = fmaf(wv[r], av[j], acc[q*4+r][j]);
            }
        }
    }
    #pragma unroll
    for (int i = 0; i < 16; ++i){
        ushort4 pk;
        pk.x = f2bf(acc[i][0]); pk.y = f2bf(acc[i][1]);
        pk.z = f2bf(acc[i][2]); pk.w = f2bf(acc[i][3]);
        *(ushort4*)&yout[(size_t)(o0+i)*NT + s0 + sb*4] = pk;
    }
}

// ---------------------------------------------------------------------------
// conv3 via MFMA: A = activations (m=sample), B = W3 (n=channel) -> D row =
// sample. Epilogue: 8-value in-reg reduce + 2-stage cross-quad butterfly;
// gmax/gmin [group][o] coalesced. Stage-A LDS addresses XOR-swizzled by
// (mtg&7) for conflict-free writes — CONSTANT register indexing only (the
// r12 runtime-index stagger spilled rb[] to scratch: 82 MB writes, 3.6x slow).
// ---------------------------------------------------------------------------
__global__ __launch_bounds__(256) void k_conv3m(const u16* __restrict__ yin,
                                                const float* __restrict__ W3,
                                                const float* __restrict__ prm,
                                                float* __restrict__ gsum, float* __restrict__ gsq,
                                                float* __restrict__ gmax, float* __restrict__ gmin){
    __shared__ uint4 bfA[2048];     // act frags: (mtg*2+kk)*64 + (lane64 ^ (mtg&7))  (32 KB)
    __shared__ uint4 bfB[1024];     // W3 frags:  (nt*2+kk)*64 + lane                 (16 KB)
    __shared__ float sS[64], sT[64];
    __shared__ float sSum[128], sSq[128];
    const int t  = threadIdx.x;
    const int s0 = blockIdx.x * 256;

    if (t < 64){ sS[t] = prm[t]; sT[t] = prm[64 + t]; }
    if (t < 128){ sSum[t] = 0.0f; sSq[t] = 0.0f; }
    __syncthreads();

    // stage B: W3 [128][64] f32 -> bf16 frags (n=channel within tile)
    #pragma unroll
    for (int rep = 0; rep < 4; ++rep){
        int cid = rep*256 + t;
        int ln  = cid & 63;
        int kk  = (cid >> 6) & 1;
        int nt  = cid >> 7;
        int o   = nt*16 + (ln & 15);
        int k0  = kk*32 + (ln >> 4)*8;
        const float* wp = &W3[o*64 + k0];
        unsigned int d[4];
        #pragma unroll
        for (int h = 0; h < 4; ++h)
            d[h] = (unsigned int)f2bf(wp[2*h]) | (((unsigned int)f2bf(wp[2*h+1])) << 16);
        bfB[cid] = make_uint4(d[0], d[1], d[2], d[3]);
    }

    // stage A: y2 channel-major; affine+relu; m=sample frags, XOR-swizzled
    {
        int oct = t >> 5;            // channels oct*8..+7: kk=oct>>2, qd=oct&3
        int sg  = t & 31;            // samples sg*8..+7 (local)
        int c0  = oct*8;
        int kk  = oct >> 2;
        int qd  = oct & 3;
        u16 rb[8][8];                // [j (=c-c0)][i (=sample)] — constant-indexed only
        #pragma unroll
        for (int j = 0; j < 8; ++j){
            int c = c0 + j;
            uint4 pk = *(const uint4*)&yin[(size_t)c*NT + s0 + sg*8];
            float sc = sS[c], tb = sT[c];
            unsigned int w4[4] = {pk.x, pk.y, pk.z, pk.w};
            #pragma unroll
            for (int h = 0; h < 4; ++h){
                rb[j][2*h]   = f2bf(fmaxf(fmaf(bf2f((u16)(w4[h] & 0xFFFF)), sc, tb), 0.0f));
                rb[j][2*h+1] = f2bf(fmaxf(fmaf(bf2f((u16)(w4[h] >> 16)),   sc, tb), 0.0f));
            }
        }
        #pragma unroll
        for (int i = 0; i < 8; ++i){            // i is a literal after unroll
            int s   = sg*8 + i;
            int mtg = s >> 4, m15 = s & 15;
            int l64 = qd*16 + m15;
            int cb  = (mtg*2 + kk)*64 + (l64 ^ (mtg & 7));   // XOR swizzle
            unsigned int d[4];
            #pragma unroll
            for (int h = 0; h < 4; ++h)
                d[h] = (unsigned int)rb[2*h][i] | (((unsigned int)rb[2*h+1][i]) << 16);
            bfA[cb] = make_uint4(d[0], d[1], d[2], d[3]);
        }
    }
    __syncthreads();

    // MFMA: wave w -> m-tiles 4w..4w+3 (samples w*64..+63), all 8 n-tiles
    const int w = t >> 6, lane = t & 63;
    f32x4 acc[4][8];
    #pragma unroll
    for (int mt = 0; mt < 4; ++mt)
        #pragma unroll
        for (int nt = 0; nt < 8; ++nt)
            acc[mt][nt] = (f32x4){0.0f, 0.0f, 0.0f, 0.0f};

    #pragma unroll
    for (int kk = 0; kk < 2; ++kk){
        short8 af[4];
        #pragma unroll
        for (int mt = 0; mt < 4; ++mt){
            int tile = 4*w + mt;
            af[mt] = *((const short8*)&bfA[(tile*2 + kk)*64 + (lane ^ (tile & 7))]);
        }
        #pragma unroll
        for (int nt = 0; nt < 8; ++nt){
            short8 bfr = *((const short8*)&bfB[(nt*2 + kk)*64 + lane]);
            #pragma unroll
            for (int mt = 0; mt < 4; ++mt)
                acc[mt][nt] = __builtin_amdgcn_mfma_f32_16x16x32_bf16(af[mt], bfr, acc[mt][nt], 0, 0, 0);
        }
    }

    // epilogue: group g (32 samples) = m-tiles (2g,2g+1). In-reg 8-value
    // reduce, then 2-stage cross-quad butterfly; quad0 writes coalesced rows.
    float stS[8], stQ[8];
    #pragma unroll
    for (int nt = 0; nt < 8; ++nt){ stS[nt] = 0.0f; stQ[nt] = 0.0f; }

    #pragma unroll
    for (int g = 0; g < 2; ++g){
        const size_t gg = (size_t)(blockIdx.x*8 + w*2 + g);
        #pragma unroll
        for (int nt = 0; nt < 8; ++nt){
            f32x4 a0 = acc[2*g][nt], a1 = acc[2*g+1][nt];
            float mx = fmaxf(fmaxf(fmaxf(a0[0], a0[1]), fmaxf(a0[2], a0[3])),
                             fmaxf(fmaxf(a1[0], a1[1]), fmaxf(a1[2], a1[3])));
            float mn = fminf(fminf(fminf(a0[0], a0[1]), fminf(a0[2], a0[3])),
                             fminf(fminf(a1[0], a1[1]), fminf(a1[2], a1[3])));
            float sm = (a0[0]+a0[1]) + (a0[2]+a0[3]) + (a1[0]+a1[1]) + (a1[2]+a1[3]);
            float sq = a0[0]*a0[0];
            sq = fmaf(a0[1], a0[1], sq); sq = fmaf(a0[2], a0[2], sq); sq = fmaf(a0[3], a0[3], sq);
            sq = fmaf(a1[0], a1[0], sq); sq = fmaf(a1[1], a1[1], sq); sq = fmaf(a1[2], a1[2], sq);
            sq = fmaf(a1[3], a1[3], sq);
            #pragma unroll
            for (int st = 16; st < 64; st <<= 1){
                mx = fmaxf(mx, __shfl_xor(mx, st, 64));
                mn = fminf(mn, __shfl_xor(mn, st, 64));
                sm += __shfl_xor(sm, st, 64);
                sq += __shfl_xor(sq, st, 64);
            }
            if (lane < 16){
                gmax[gg*128 + nt*16 + lane] = mx;
                gmin[gg*128 + nt*16 + lane] = mn;
            }
            stS[nt] += sm; stQ[nt] += sq;
        }
    }
    if (lane < 16){
        #pragma unroll
        for (int nt = 0; nt < 8; ++nt){
            atomicAdd(&sSum[nt*16 + lane], stS[nt]);
            atomicAdd(&sSq[nt*16 + lane],  stQ[nt]);
        }
    }
    __syncthreads();
    if (t < 128){
        atomicAdd(&gsum[t], sSum[t]);
        atomicAdd(&gsq[t],  sSq[t]);
    }
}

// ---------------------------------------------------------------------------
// per-channel sum/sumsq over stored y (bf16 channel-major), vectorized
// ---------------------------------------------------------------------------
__global__ __launch_bounds__(256) void k_stats(const u16* __restrict__ y,
                                               float* __restrict__ sum,
                                               float* __restrict__ sumsq){
    int c = blockIdx.x, chunk = blockIdx.y;
    size_t base = (size_t)c*NT + (size_t)chunk*16384;
    const uint2* p = (const uint2*)(y + base);
    float s = 0.0f, qq = 0.0f;
    for (int i = threadIdx.x; i < 4096; i += 256){
        uint2 v = p[i];
        float v0 = bf2f((u16)(v.x & 0xFFFF)), v1 = bf2f((u16)(v.x >> 16));
        float v2 = bf2f((u16)(v.y & 0xFFFF)), v3 = bf2f((u16)(v.y >> 16));
        s += v0 + v1 + v2 + v3;
        qq = fmaf(v0, v0, qq); qq = fmaf(v1, v1, qq);
        qq = fmaf(v2, v2, qq); qq = fmaf(v3, v3, qq);
    }
    #pragma unroll
    for (int off = 32; off > 0; off >>= 1){
        s  += __shfl_down(s,  off, 64);
        qq += __shfl_down(qq, off, 64);
    }
    __shared__ float aS[4], aQ[4];
    int wave = threadIdx.x >> 6, lane = threadIdx.x & 63;
    if (lane == 0){ aS[wave] = s; aQ[wave] = qq; }
    __syncthreads();
    if (threadIdx.x == 0){
        atomicAdd(&sum[c],   aS[0] + aS[1] + aS[2] + aS[3]);
        atomicAdd(&sumsq[c], aQ[0] + aQ[1] + aQ[2] + aQ[3]);
    }
}

// fold BN into affine: s = g*rsqrt(var+eps), t = b - mu*s
__global__ void k_fold(const float* __restrict__ sum, const float* __restrict__ sumsq,
                       const float* __restrict__ gW, const float* __restrict__ bW,
                       float* __restrict__ prm, int C){
    int c = threadIdx.x;
    if (c < C){
        const float inv = 1.0f / (float)NT;
        float mu  = sum[c] * inv;
        float var = sumsq[c] * inv - mu*mu;
        float sc  = gW[c] / sqrtf(var + 1e-5f);
        prm[c]     = sc;
        prm[C + c] = bW[c] - mu*sc;
    }
}

// out[b][o][m] = ReLU(s * (s>=0 ? gmax : gmin) + t); gmax/gmin layout [group][o]
__global__ __launch_bounds__(256) void k_final(const float* __restrict__ gmax,
                                               const float* __restrict__ gmin,
                                               const float* __restrict__ prm,
                                               float* __restrict__ out){
    int bo = blockIdx.y;
    int b = bo >> 7, o = bo & 127;
    int m = blockIdx.x*256 + threadIdx.x;
    float sc = prm[o], tt = prm[128 + o];
    size_t i = (size_t)(b*M_ + m)*128 + o;
    float v = (sc >= 0.0f) ? gmax[i] : gmin[i];
    out[((size_t)(b*128 + o))*M_ + m] = fmaxf(fmaf(v, sc, tt), 0.0f);
}

// ---------------------------------------------------------------------------
extern "C" void kernel_launch(void* const* d_in, const int* in_sizes, int n_in,
                              void* d_out, int out_size, void* d_ws, size_t ws_size,
                              hipStream_t stream){
    const float* loc  = (const float*)d_in[0];
    const float* nloc = (const float*)d_in[1];
    const float* feat = (const float*)d_in[2];
    const float* W1   = (const float*)d_in[3];
    const float* g1   = (const float*)d_in[4];
    const float* b1   = (const float*)d_in[5];
    const float* W2   = (const float*)d_in[6];
    const float* g2   = (const float*)d_in[7];
    const float* b2   = (const float*)d_in[8];
    const float* W3   = (const float*)d_in[9];
    const float* g3   = (const float*)d_in[10];
    const float* b3   = (const float*)d_in[11];
    float* out = (float*)d_out;

    char* ws = (char*)d_ws;
    float* stats = (float*)ws;                       // 512 f @ 0
    float* prm1  = (float*)(ws + 2048);              // 128 f
    float* prm2  = (float*)(ws + 2048 + 512);        // 128 f
    float* prm3  = (float*)(ws + 2048 + 1024);       // 256 f -> ends 4096
    int*   idx   = (int*)(ws + 4096);                // 2 MB
    float* gmax  = (float*)(ws + 2101248);           // 8 MB [BM][128]
    float* gmin  = (float*)(ws + 10489856);          // 8 MB
    float* featT = (float*)(ws + 18878464);          // 16 MB [B][N][64]
    u16*   y1    = (u16*)(ws + 35655680);            // 64 MB [64][NT]
    u16*   y2    = (u16*)(ws + 102764544);           // 64 MB  (ws >= 170 MB proven)

    hipMemsetAsync(stats, 0, 2048, stream);

    k_feat<<<dim3(N_/64, B_), 256, 0, stream>>>(feat, featT);
    k_knn<<<B_*M_, 256, 0, stream>>>(loc, nloc, idx);

    k_conv1t<<<NT/256, 256, 0, stream>>>(idx, loc, nloc, featT, W1, y1);
    k_stats<<<dim3(64, 32), 256, 0, stream>>>(y1, stats + 0, stats + 64);
    k_fold<<<1, 128, 0, stream>>>(stats + 0, stats + 64, g1, b1, prm1, 64);

    k_conv2t<<<NT/256, 256, 0, stream>>>(y1, W2, prm1, y2);
    k_stats<<<dim3(64, 32), 256, 0, stream>>>(y2, stats + 128, stats + 192);
    k_fold<<<1, 128, 0, stream>>>(stats + 128, stats + 192, g2, b2, prm2, 64);

    k_conv3m<<<NT/256, 256, 0, stream>>>(y2, W3, prm2, stats + 256, stats + 384, gmax, gmin);
    k_fold<<<1, 128, 0, stream>>>(stats + 256, stats + 384, g3, b3, prm3, 128);

    k_final<<<dim3(M_/256, B_*128), 256, 0, stream>>>(gmax, gmin, prm3, out);
}